// Round 6
// baseline (524.965 us; speedup 1.0000x reference)
//
#include <hip/hip_runtime.h>
#include <hip/hip_bf16.h>

// Problem constants
#define HH   8
#define Bb   8
#define Kk   64
#define Nn   16384
#define DQd  256
#define EPSf 1e-5f
#define NCH  32      // n-chunks for attention
#define CHK  512     // rows per chunk (Nn / NCH)
#define SUB  32      // rows per subtile
#define NSUB (CHK / SUB)   // 16

typedef __bf16 bf16_t;
typedef __bf16 bf16x8 __attribute__((ext_vector_type(8)));
typedef __bf16 bf16x4 __attribute__((ext_vector_type(4)));
typedef __bf16 bf16x2 __attribute__((ext_vector_type(2)));
typedef float  f32x4  __attribute__((ext_vector_type(4)));
typedef float  f32x16 __attribute__((ext_vector_type(16)));

#define MFMA16(a, b, c) __builtin_amdgcn_mfma_f32_16x16x32_bf16((a), (b), (c), 0, 0, 0)
#define MFMA32(a, b, c) __builtin_amdgcn_mfma_f32_32x32x16_bf16((a), (b), (c), 0, 0, 0)

// q-scale: 1/sqrt(64) * log2(e)  (exp folded to exp2 in k3)
#define QSCALE 0.1803368801111f

static __device__ __forceinline__ int pk2(float x, float y) {
    bf16x2 v; v[0] = (bf16_t)x; v[1] = (bf16_t)y;
    return __builtin_bit_cast(int, v);
}

// Pack a 32x32 MFMA D-tile T (cols = l31, rows scattered (r&3)+8*(r>>2)+4*hi)
// into 2 B-like fragments: out[kc] elem j at lane (l31,hi) = T[kc*16+hi*8+j][l31].
// Harness-verified shfl formulation (rounds 0-1).
static __device__ __forceinline__ void pack_tile(const f32x16 Sv, int hi, bf16x8* out) {
    #pragma unroll
    for (int kc = 0; kc < 2; ++kc) {
        const int oc = kc * 8;
        int Lp0 = pk2(Sv[oc + 0], Sv[oc + 1]);
        int Lp1 = pk2(Sv[oc + 2], Sv[oc + 3]);
        int Hp0 = pk2(Sv[oc + 4], Sv[oc + 5]);
        int Hp1 = pk2(Sv[oc + 6], Sv[oc + 7]);
        int Lx0 = __shfl_xor(Lp0, 32, 64);
        int Lx1 = __shfl_xor(Lp1, 32, 64);
        int Hx0 = __shfl_xor(Hp0, 32, 64);
        int Hx1 = __shfl_xor(Hp1, 32, 64);
        int4 bi;
        bi.x = hi ? Hx0 : Lp0;
        bi.y = hi ? Hx1 : Lp1;
        bi.z = hi ? Hp0 : Lx0;
        bi.w = hi ? Hp1 : Lx1;
        out[kc] = __builtin_bit_cast(bf16x8, bi);
    }
}

static __device__ __forceinline__ void store8(bf16_t* dst, float4 a, float4 b) {
    bf16x8 o;
    o[0] = (bf16_t)a.x; o[1] = (bf16_t)a.y; o[2] = (bf16_t)a.z; o[3] = (bf16_t)a.w;
    o[4] = (bf16_t)b.x; o[5] = (bf16_t)b.y; o[6] = (bf16_t)b.z; o[7] = (bf16_t)b.w;
    *(bf16x8*)dst = o;
}

// ---------------------------------------------------------------------------
// Kernel 1: LN1 + q = norm @ Wq_h (scaled QSCALE) + q_tilde = q @ Wk_h^T -> bf16
// Blocks 64..71 additionally produce WvT[h*64+dv][d] bf16 (transposed Wv).
// ---------------------------------------------------------------------------
__global__ __launch_bounds__(256) void k1_qt(
    const float* __restrict__ slots, const float* __restrict__ g1,
    const float* __restrict__ bb1, const float* __restrict__ Wq,
    const float* __restrict__ Wk, const float* __restrict__ Wv,
    bf16_t* __restrict__ qt, bf16_t* __restrict__ WvT)
{
    __shared__ alignas(16) bf16_t nrow[64][264];
    __shared__ alignas(16) bf16_t wqT[64][264];
    __shared__ alignas(16) bf16_t qb[64][72];
    __shared__ alignas(16) bf16_t wkT[256][72];

    if (blockIdx.x >= 64) {
        const int h = blockIdx.x - 64;
        const int t = threadIdx.x;
        const int dv = t & 63, dq = t >> 6;
        #pragma unroll
        for (int i = 0; i < 16; ++i) {
            int d = dq * 64 + i * 4;
            bf16x4 o;
            #pragma unroll
            for (int j = 0; j < 4; ++j)
                o[j] = (bf16_t)Wv[(size_t)(d + j) * 512 + h * 64 + dv];
            *(bf16x4*)&WvT[(size_t)(h * 64 + dv) * 256 + d] = o;
        }
        return;
    }

    const int b = blockIdx.x >> 3, h = blockIdx.x & 7;
    const int t = threadIdx.x;
    const int w = t >> 6, lane = t & 63;
    const int l15 = lane & 15, quad = lane >> 4;

    {
        float4 gv = *(const float4*)&g1[lane * 4];
        float4 bv = *(const float4*)&bb1[lane * 4];
        #pragma unroll 2
        for (int i = 0; i < 16; ++i) {
            int row = w * 16 + i;
            float4 x = *(const float4*)&slots[((size_t)b * Kk + row) * DQd + lane * 4];
            float s = x.x + x.y + x.z + x.w;
            for (int m = 1; m < 64; m <<= 1) s += __shfl_xor(s, m, 64);
            float mean = s * (1.0f / 256.0f);
            float dx = x.x - mean, dy = x.y - mean, dz = x.z - mean, dw = x.w - mean;
            float v2 = dx * dx + dy * dy + dz * dz + dw * dw;
            for (int m = 1; m < 64; m <<= 1) v2 += __shfl_xor(v2, m, 64);
            float rs = rsqrtf(v2 * (1.0f / 256.0f) + EPSf);
            bf16x4 o;
            o[0] = (bf16_t)(dx * rs * gv.x + bv.x);
            o[1] = (bf16_t)(dy * rs * gv.y + bv.y);
            o[2] = (bf16_t)(dz * rs * gv.z + bv.z);
            o[3] = (bf16_t)(dw * rs * gv.w + bv.w);
            *(bf16x4*)&nrow[row][lane * 4] = o;
        }
    }
    {
        int d = t & 63, r4 = t >> 6;
        #pragma unroll 8
        for (int p = 0; p < 64; ++p) {
            int i = r4 + p * 4;
            wqT[d][i] = (bf16_t)Wq[(size_t)i * 512 + h * 64 + d];
            wkT[i][d] = (bf16_t)Wk[(size_t)i * 512 + h * 64 + d];
        }
    }
    __syncthreads();

    f32x4 acc1[4] = {};
    for (int ks = 0; ks < 8; ++ks) {
        bf16x8 a = *(const bf16x8*)&nrow[w * 16 + l15][ks * 32 + quad * 8];
        #pragma unroll
        for (int tt = 0; tt < 4; ++tt) {
            bf16x8 bfr = *(const bf16x8*)&wqT[tt * 16 + l15][ks * 32 + quad * 8];
            acc1[tt] = MFMA16(a, bfr, acc1[tt]);
        }
    }
    #pragma unroll
    for (int tt = 0; tt < 4; ++tt)
        #pragma unroll
        for (int r = 0; r < 4; ++r)
            qb[w * 16 + quad * 4 + r][tt * 16 + l15] = (bf16_t)(acc1[tt][r] * QSCALE);
    __syncthreads();

    f32x4 acc2[16] = {};
    for (int ks = 0; ks < 2; ++ks) {
        bf16x8 a = *(const bf16x8*)&qb[w * 16 + l15][ks * 32 + quad * 8];
        #pragma unroll
        for (int tt = 0; tt < 16; ++tt) {
            bf16x8 bfr = *(const bf16x8*)&wkT[tt * 16 + l15][ks * 32 + quad * 8];
            acc2[tt] = MFMA16(a, bfr, acc2[tt]);
        }
    }
    size_t base = (size_t)(b * HH + h) * 64;
    #pragma unroll
    for (int tt = 0; tt < 16; ++tt)
        #pragma unroll
        for (int r = 0; r < 4; ++r)
            qt[(base + w * 16 + quad * 4 + r) * 256 + tt * 16 + l15] = (bf16_t)acc2[tt][r];
}

// ---------------------------------------------------------------------------
// Kernel 3: flash attention, v = hit@Wv on the fly. MERGED: one 1024-thread
// block serves ALL 8 heads (16 waves = 8 heads x 2 q-halves) -> hit staged
// and read ONCE (was twice), grid 256 = b(8) x c(32), 4 waves/SIMD.
// Schedule is r4-exact (proven spill-free): MFMA cluster -> stage next ->
// prefetch -> exp2 -> pack -> vb write -> barrier -> PV. No setprio.
// Hazards: every producer/consumer pair on hs[x]/vb[x] separated by exactly
// one block barrier (buffers alternate per subtile).
// ---------------------------------------------------------------------------
__global__ __launch_bounds__(1024) void k3_attn(
    const float* __restrict__ hit, const bf16_t* __restrict__ qt,
    const bf16_t* __restrict__ WvT, bf16_t* __restrict__ nump,
    float* __restrict__ lp)
{
    __shared__ alignas(16) bf16_t hs[2][SUB * 256];   // 2 x 16KB, granule-swizzled
    __shared__ alignas(16) bf16_t vb[2][32 * 512];    // 2 x 32KB v-frag exchange

    const int bid = blockIdx.x;
    const int c  = bid & 31;
    const int b  = bid >> 5;
    const int t  = threadIdx.x;
    const int w = t >> 6, lane = t & 63;
    const int l31 = lane & 31, hi = lane >> 5;
    const int hl = w >> 1;             // head 0..7
    const int qh = w & 1;              // q-half owned == dv-half owned
    const int bh = b * HH + hl;

    bf16x8 qf[16], wf[16];
    {
        const bf16_t* qrow = qt + ((size_t)bh * 64 + qh * 32 + l31) * 256 + hi * 8;
        const bf16_t* wrow = WvT + ((size_t)(hl * 64 + qh * 32 + l31)) * 256 + hi * 8;
        #pragma unroll
        for (int ks = 0; ks < 16; ++ks) {
            qf[ks] = *(const bf16x8*)(qrow + ks * 16);
            wf[ks] = *(const bf16x8*)(wrow + ks * 16);
        }
    }

    f32x16 accO = {};   // dv-tile == qh
    f32x16 accX = {};   // dv-tile == 1-qh
    float ls = 0.f;

    const float* hbase = hit + ((size_t)b * Nn + c * CHK) * 256;
    const int row0 = t >> 5, g0 = t & 31;   // 1024 thr = 32 rows x 32 col-granules
    const int sw0 = (g0 ^ (row0 & 7)) * 8;

    float4 pA0, pA1;
#define PREFETCH(ss) do { \
        const float* s0_ = hbase + (size_t)(ss) * SUB * 256 + (size_t)row0 * 256 + g0 * 8; \
        pA0 = ((const float4*)s0_)[0]; pA1 = ((const float4*)s0_)[1]; \
    } while (0)

    // prologue: stage subtile 0, prefetch subtile 1
    PREFETCH(0);
    store8(&hs[0][row0 * 256 + sw0], pA0, pA1);
    PREFETCH(1);
    __syncthreads();

    const int xr = l31 & 7;

    for (int s = 0; s < NSUB; ++s) {
        const int cur = s & 1;
        const bf16_t* hrow = &hs[cur][l31 * 256];

        // Fused S and v over the 256-d contraction: one A-read feeds 2 MFMAs.
        f32x16 St = {}, Vt = {};
        #pragma unroll
        for (int ks = 0; ks < 16; ++ks) {
            bf16x8 A = *(const bf16x8*)(hrow + (((2 * ks + hi) ^ xr) * 8));
            Vt = MFMA32(A, wf[ks], Vt);
            St = MFMA32(A, qf[ks], St);
        }

        // stage next subtile into the alternate buffer; prefetch s+2
        if (s + 1 < NSUB)
            store8(&hs[cur ^ 1][row0 * 256 + sw0], pA0, pA1);
        if (s + 2 < NSUB) PREFETCH(s + 2);

        // exp2 (scale folded into qt in k1)
        #pragma unroll
        for (int r = 0; r < 16; ++r) {
            float e = exp2f(St[r]);
            St[r] = e;
            ls += e;
        }
        bf16x8 Pf[2];
        pack_tile(St, hi, Pf);
        {
            bf16x8 Vf[2];
            pack_tile(Vt, hi, Vf);
            *(bf16x8*)&vb[cur][((hl * 2 + 0) * 2 + qh) * 512 + lane * 8] = Vf[0];
            *(bf16x8*)&vb[cur][((hl * 2 + 1) * 2 + qh) * 512 + lane * 8] = Vf[1];
        }   // Vf dies here (pre-barrier)
        __syncthreads();   // the ONLY barrier in the loop

        {
            bf16x8 vo0 = *(const bf16x8*)&vb[cur][((hl * 2 + 0) * 2 + qh) * 512 + lane * 8];
            bf16x8 vx0 = *(const bf16x8*)&vb[cur][((hl * 2 + 0) * 2 + (1 - qh)) * 512 + lane * 8];
            bf16x8 vo1 = *(const bf16x8*)&vb[cur][((hl * 2 + 1) * 2 + qh) * 512 + lane * 8];
            bf16x8 vx1 = *(const bf16x8*)&vb[cur][((hl * 2 + 1) * 2 + (1 - qh)) * 512 + lane * 8];
            accO = MFMA32(Pf[0], vo0, accO);
            accX = MFMA32(Pf[0], vx0, accX);
            accO = MFMA32(Pf[1], vo1, accO);
            accX = MFMA32(Pf[1], vx1, accX);
        }
    }
#undef PREFETCH

    {
        float lt = ls + __shfl_xor(ls, 32, 64);
        if (hi == 0)
            lp[((size_t)bh * NCH + c) * 64 + qh * 32 + l31] = lt;
    }
    {
        size_t nbase = ((size_t)bh * NCH + c) * 64 * 64;
        #pragma unroll
        for (int r = 0; r < 16; ++r) {
            int q = qh * 32 + (r & 3) + 8 * (r >> 2) + 4 * hi;
            size_t ro = nbase + (size_t)q * 64;
            nump[ro + qh * 32 + l31]       = (bf16_t)accO[r];
            nump[ro + (1 - qh) * 32 + l31] = (bf16_t)accX[r];
        }
    }
}

// ---------------------------------------------------------------------------
// Kernel 3.5 (combine): X[b*64+q][h*64+dv] = (sum_c num) / (sum_c l), bf16.
// grid 128 = bh(64) x qh(2); 256 thr: thread (q = qh*32 + t>>3, g = t&7)
// owns 8 dv columns. Fully coalesced bf16x8 loads (16B/lane).
// ---------------------------------------------------------------------------
__global__ __launch_bounds__(256) void k35_comb(
    const bf16_t* __restrict__ nump, const float* __restrict__ lp,
    bf16_t* __restrict__ X)
{
    const int bh = blockIdx.x >> 1, qhb = blockIdx.x & 1;
    const int b = bh >> 3, h = bh & 7;
    const int t = threadIdx.x;
    const int q = qhb * 32 + (t >> 3), g = t & 7;
    float s8[8] = {};
    float lsum = 0.f;
    #pragma unroll 4
    for (int cc = 0; cc < NCH; ++cc) {
        size_t base = ((size_t)bh * NCH + cc) * 64 + q;
        bf16x8 v = *(const bf16x8*)&nump[base * 64 + g * 8];
        #pragma unroll
        for (int j = 0; j < 8; ++j) s8[j] += (float)v[j];
        lsum += lp[base];
    }
    float inv = 1.0f / lsum;
    bf16x8 o;
    #pragma unroll
    for (int j = 0; j < 8; ++j) o[j] = (bf16_t)(s8[j] * inv);
    *(bf16x8*)&X[((size_t)b * 64 + q) * 512 + h * 64 + g * 8] = o;
}

// ---------------------------------------------------------------------------
// Kernel 4a: H = relu(X @ W1 + b1). X:[512,512] bf16 (L2-resident, read
// direct from global — no LDS staging), W1:[512,512] f32. grid 256 =
// rt(16, 32 rows) x ct(16, 32 cols); 64 thr = 1 wave per 32x32 tile.
// ---------------------------------------------------------------------------
__global__ __launch_bounds__(64) void k4a_mlp1(
    const bf16_t* __restrict__ X, const float* __restrict__ W1,
    const float* __restrict__ b1, bf16_t* __restrict__ H)
{
    __shared__ float scr[32 * 33];
    const int rt = blockIdx.x >> 4, ct = blockIdx.x & 15;
    const int lane = threadIdx.x, l31 = lane & 31, hi = lane >> 5;
    const int colbase = ct * 32;

    const bf16_t* xrow = X + ((size_t)(rt * 32 + l31)) * 512 + hi * 8;
    f32x16 acc = {};
    #pragma unroll 4
    for (int kc = 0; kc < 32; ++kc) {
        bf16x8 af;
        #pragma unroll
        for (int j = 0; j < 8; ++j)
            af[j] = (bf16_t)W1[(size_t)(kc * 16 + hi * 8 + j) * 512 + colbase + l31];
        bf16x8 bfr = *(const bf16x8*)(xrow + kc * 16);
        acc = MFMA32(af, bfr, acc);
    }
    const float bia = b1[colbase + l31];
    #pragma unroll
    for (int r = 0; r < 16; ++r) {
        int m = (r & 3) + 8 * (r >> 2) + 4 * hi;
        scr[m * 33 + l31] = acc[r];
    }
    __syncthreads();
    #pragma unroll
    for (int j = 0; j < 16; ++j) {
        float v = scr[l31 * 33 + hi * 16 + j] + bia;
        v = fmaxf(v, 0.f);
        H[((size_t)(rt * 32 + hi * 16 + j)) * 512 + colbase + l31] = (bf16_t)v;
    }
}

// ---------------------------------------------------------------------------
// Kernel 4b: y = H @ W2 + b2 + slots (residual) -> ys (f32). H read direct
// from global (L2-resident). grid 128 = b(8) x rtt(2, 32 rows) x ct(8, 32
// cols); 64 thr = 1 wave per 32x32 tile. LN2 in k4c.
// ---------------------------------------------------------------------------
__global__ __launch_bounds__(64) void k4b_gemm(
    const bf16_t* __restrict__ H, const float* __restrict__ W2,
    const float* __restrict__ b2, const float* __restrict__ slots,
    float* __restrict__ ys)
{
    __shared__ float scr[32 * 33];
    const int b = blockIdx.x >> 4, rtt = (blockIdx.x >> 3) & 1, ct = blockIdx.x & 7;
    const int lane = threadIdx.x, l31 = lane & 31, hi = lane >> 5;
    const int colbase = ct * 32;
    const int rowbase = b * 64 + rtt * 32;

    const bf16_t* hrow = H + ((size_t)(rowbase + l31)) * 512 + hi * 8;
    f32x16 acc = {};
    #pragma unroll 4
    for (int kc = 0; kc < 32; ++kc) {
        bf16x8 af;
        #pragma unroll
        for (int j = 0; j < 8; ++j)
            af[j] = (bf16_t)W2[(size_t)(kc * 16 + hi * 8 + j) * 256 + colbase + l31];
        bf16x8 bfr = *(const bf16x8*)(hrow + kc * 16);
        acc = MFMA32(af, bfr, acc);
    }
    const float b2c = b2[colbase + l31];
    #pragma unroll
    for (int r = 0; r < 16; ++r) {
        int m = (r & 3) + 8 * (r >> 2) + 4 * hi;
        scr[m * 33 + l31] = acc[r];
    }
    __syncthreads();
    #pragma unroll
    for (int j = 0; j < 16; ++j) {
        int row = rowbase + hi * 16 + j;
        float v = scr[l31 * 33 + hi * 16 + j] + b2c
                + slots[(size_t)row * 256 + colbase + l31];
        ys[(size_t)row * 256 + colbase + l31] = v;
    }
}

// ---------------------------------------------------------------------------
// Kernel 4c: LN2(ys) -> out. grid 64 x 256 thr; each wave does 2 rows.
// ---------------------------------------------------------------------------
__global__ __launch_bounds__(256) void k4c_ln2(
    const float* __restrict__ ys, const float* __restrict__ g2,
    const float* __restrict__ bb2, float* __restrict__ out)
{
    const int t = threadIdx.x;
    const int w = t >> 6, lane = t & 63;
    float4 gv = *(const float4*)&g2[lane * 4];
    float4 bv = *(const float4*)&bb2[lane * 4];
    #pragma unroll
    for (int rr = 0; rr < 2; ++rr) {
        int row = blockIdx.x * 8 + w * 2 + rr;
        float4 x = *(const float4*)&ys[(size_t)row * 256 + lane * 4];
        float s = x.x + x.y + x.z + x.w;
        for (int m = 1; m < 64; m <<= 1) s += __shfl_xor(s, m, 64);
        float mean = s * (1.0f / 256.0f);
        float dx = x.x - mean, dy = x.y - mean, dz = x.z - mean, dw = x.w - mean;
        float v2 = dx * dx + dy * dy + dz * dz + dw * dw;
        for (int m = 1; m < 64; m <<= 1) v2 += __shfl_xor(v2, m, 64);
        float rs = rsqrtf(v2 * (1.0f / 256.0f) + EPSf);
        float4 o;
        o.x = dx * rs * gv.x + bv.x;
        o.y = dy * rs * gv.y + bv.y;
        o.z = dz * rs * gv.z + bv.z;
        o.w = dw * rs * gv.w + bv.w;
        *(float4*)&out[(size_t)row * 256 + lane * 4] = o;
    }
}

// ---------------------------------------------------------------------------
extern "C" void kernel_launch(void* const* d_in, const int* in_sizes, int n_in,
                              void* d_out, int out_size, void* d_ws, size_t ws_size,
                              hipStream_t stream) {
    (void)in_sizes; (void)n_in; (void)out_size; (void)ws_size;
    const float* slots = (const float*)d_in[0];
    const float* hit   = (const float*)d_in[1];
    const float* g1    = (const float*)d_in[2];
    const float* bb1   = (const float*)d_in[3];
    const float* Wq    = (const float*)d_in[4];
    const float* Wk    = (const float*)d_in[5];
    const float* Wv    = (const float*)d_in[6];
    const float* W1    = (const float*)d_in[7];
    const float* b1v   = (const float*)d_in[8];
    const float* W2    = (const float*)d_in[9];
    const float* b2v   = (const float*)d_in[10];
    const float* g2    = (const float*)d_in[11];
    const float* bb2   = (const float*)d_in[12];
    float* out = (float*)d_out;

    // workspace layout (~19.75 MB):
    // qt 2MB (reused as ys 512KB after k3) | WvT 256KB | nump bf16 16MB |
    // lp 512KB | X 512KB | H 512KB
    char* wsp = (char*)d_ws;
    bf16_t* qt   = (bf16_t*)wsp;
    float*  ys   = (float*) wsp;   // overlays qt (dead after k3_attn)
    bf16_t* WvT  = (bf16_t*)(wsp + (size_t)2097152);
    bf16_t* nump = (bf16_t*)(wsp + (size_t)2359296);
    float*  lp   = (float*) (wsp + (size_t)19136512);
    bf16_t* X    = (bf16_t*)(wsp + (size_t)19660800);
    bf16_t* H    = (bf16_t*)(wsp + (size_t)20185088);

    hipLaunchKernelGGL(k1_qt, dim3(72), dim3(256), 0, stream,
                       slots, g1, bb1, Wq, Wk, Wv, qt, WvT);
    hipLaunchKernelGGL(k3_attn, dim3(Bb * NCH), dim3(1024), 0, stream,
                       hit, qt, WvT, nump, lp);
    hipLaunchKernelGGL(k35_comb, dim3(128), dim3(256), 0, stream,
                       nump, lp, X);
    hipLaunchKernelGGL(k4a_mlp1, dim3(256), dim3(64), 0, stream,
                       X, W1, b1v, H);
    hipLaunchKernelGGL(k4b_gemm, dim3(128), dim3(64), 0, stream,
                       H, W2, b2v, slots, ys);
    hipLaunchKernelGGL(k4c_ln2, dim3(64), dim3(256), 0, stream,
                       ys, g2, bb2, out);
}

// Round 7
// 291.936 us; speedup vs baseline: 1.7982x; 1.7982x over previous
//
#include <hip/hip_runtime.h>
#include <hip/hip_bf16.h>

// Problem constants
#define HH   8
#define Bb   8
#define Kk   64
#define Nn   16384
#define DQd  256
#define EPSf 1e-5f
#define NCH  32      // n-chunks for attention
#define CHK  512     // rows per chunk (Nn / NCH)
#define SUB  32      // rows per subtile
#define NSUB (CHK / SUB)   // 16

typedef __bf16 bf16_t;
typedef __bf16 bf16x8 __attribute__((ext_vector_type(8)));
typedef __bf16 bf16x4 __attribute__((ext_vector_type(4)));
typedef __bf16 bf16x2 __attribute__((ext_vector_type(2)));
typedef float  f32x4  __attribute__((ext_vector_type(4)));
typedef float  f32x16 __attribute__((ext_vector_type(16)));

#define MFMA16(a, b, c) __builtin_amdgcn_mfma_f32_16x16x32_bf16((a), (b), (c), 0, 0, 0)
#define MFMA32(a, b, c) __builtin_amdgcn_mfma_f32_32x32x16_bf16((a), (b), (c), 0, 0, 0)

static __device__ __forceinline__ int pk2(float x, float y) {
    bf16x2 v; v[0] = (bf16_t)x; v[1] = (bf16_t)y;
    return __builtin_bit_cast(int, v);
}

// Pack a 32x32 MFMA D-tile T (cols = l31, rows scattered (r&3)+8*(r>>2)+4*hi)
// into 2 B-like fragments: out[kc] elem j at lane (l31,hi) = T[kc*16+hi*8+j][l31].
// Harness-verified shfl formulation (rounds 0-1).
static __device__ __forceinline__ void pack_tile(const f32x16 Sv, int hi, bf16x8* out) {
    #pragma unroll
    for (int kc = 0; kc < 2; ++kc) {
        const int oc = kc * 8;
        int Lp0 = pk2(Sv[oc + 0], Sv[oc + 1]);
        int Lp1 = pk2(Sv[oc + 2], Sv[oc + 3]);
        int Hp0 = pk2(Sv[oc + 4], Sv[oc + 5]);
        int Hp1 = pk2(Sv[oc + 6], Sv[oc + 7]);
        int Lx0 = __shfl_xor(Lp0, 32, 64);
        int Lx1 = __shfl_xor(Lp1, 32, 64);
        int Hx0 = __shfl_xor(Hp0, 32, 64);
        int Hx1 = __shfl_xor(Hp1, 32, 64);
        int4 bi;
        bi.x = hi ? Hx0 : Lp0;
        bi.y = hi ? Hx1 : Lp1;
        bi.z = hi ? Hp0 : Lx0;
        bi.w = hi ? Hp1 : Lx1;
        out[kc] = __builtin_bit_cast(bf16x8, bi);
    }
}

static __device__ __forceinline__ void store8(bf16_t* dst, float4 a, float4 b) {
    bf16x8 o;
    o[0] = (bf16_t)a.x; o[1] = (bf16_t)a.y; o[2] = (bf16_t)a.z; o[3] = (bf16_t)a.w;
    o[4] = (bf16_t)b.x; o[5] = (bf16_t)b.y; o[6] = (bf16_t)b.z; o[7] = (bf16_t)b.w;
    *(bf16x8*)dst = o;
}

// ---------------------------------------------------------------------------
// Kernel 1: LN1 + q = norm @ Wq_h (scaled 1/8) + q_tilde = q @ Wk_h^T -> bf16
// Blocks 64..71 additionally produce WvT[h*64+dv][d] bf16 (transposed Wv).
// (Round-4-exact, measured-good.)
// ---------------------------------------------------------------------------
__global__ __launch_bounds__(256) void k1_qt(
    const float* __restrict__ slots, const float* __restrict__ g1,
    const float* __restrict__ bb1, const float* __restrict__ Wq,
    const float* __restrict__ Wk, const float* __restrict__ Wv,
    bf16_t* __restrict__ qt, bf16_t* __restrict__ WvT)
{
    __shared__ alignas(16) bf16_t nrow[64][264];
    __shared__ alignas(16) bf16_t wqT[64][264];
    __shared__ alignas(16) bf16_t qb[64][72];
    __shared__ alignas(16) bf16_t wkT[256][72];

    if (blockIdx.x >= 64) {
        const int h = blockIdx.x - 64;
        const int t = threadIdx.x;
        const int dv = t & 63, dq = t >> 6;
        #pragma unroll
        for (int i = 0; i < 16; ++i) {
            int d = dq * 64 + i * 4;
            bf16x4 o;
            #pragma unroll
            for (int j = 0; j < 4; ++j)
                o[j] = (bf16_t)Wv[(size_t)(d + j) * 512 + h * 64 + dv];
            *(bf16x4*)&WvT[(size_t)(h * 64 + dv) * 256 + d] = o;
        }
        return;
    }

    const int b = blockIdx.x >> 3, h = blockIdx.x & 7;
    const int t = threadIdx.x;
    const int w = t >> 6, lane = t & 63;
    const int l15 = lane & 15, quad = lane >> 4;

    {
        float4 gv = *(const float4*)&g1[lane * 4];
        float4 bv = *(const float4*)&bb1[lane * 4];
        #pragma unroll 2
        for (int i = 0; i < 16; ++i) {
            int row = w * 16 + i;
            float4 x = *(const float4*)&slots[((size_t)b * Kk + row) * DQd + lane * 4];
            float s = x.x + x.y + x.z + x.w;
            for (int m = 1; m < 64; m <<= 1) s += __shfl_xor(s, m, 64);
            float mean = s * (1.0f / 256.0f);
            float dx = x.x - mean, dy = x.y - mean, dz = x.z - mean, dw = x.w - mean;
            float v2 = dx * dx + dy * dy + dz * dz + dw * dw;
            for (int m = 1; m < 64; m <<= 1) v2 += __shfl_xor(v2, m, 64);
            float rs = rsqrtf(v2 * (1.0f / 256.0f) + EPSf);
            bf16x4 o;
            o[0] = (bf16_t)(dx * rs * gv.x + bv.x);
            o[1] = (bf16_t)(dy * rs * gv.y + bv.y);
            o[2] = (bf16_t)(dz * rs * gv.z + bv.z);
            o[3] = (bf16_t)(dw * rs * gv.w + bv.w);
            *(bf16x4*)&nrow[row][lane * 4] = o;
        }
    }
    {
        int d = t & 63, r4 = t >> 6;
        #pragma unroll 8
        for (int p = 0; p < 64; ++p) {
            int i = r4 + p * 4;
            wqT[d][i] = (bf16_t)Wq[(size_t)i * 512 + h * 64 + d];
            wkT[i][d] = (bf16_t)Wk[(size_t)i * 512 + h * 64 + d];
        }
    }
    __syncthreads();

    f32x4 acc1[4] = {};
    for (int ks = 0; ks < 8; ++ks) {
        bf16x8 a = *(const bf16x8*)&nrow[w * 16 + l15][ks * 32 + quad * 8];
        #pragma unroll
        for (int tt = 0; tt < 4; ++tt) {
            bf16x8 bfr = *(const bf16x8*)&wqT[tt * 16 + l15][ks * 32 + quad * 8];
            acc1[tt] = MFMA16(a, bfr, acc1[tt]);
        }
    }
    #pragma unroll
    for (int tt = 0; tt < 4; ++tt)
        #pragma unroll
        for (int r = 0; r < 4; ++r)
            qb[w * 16 + quad * 4 + r][tt * 16 + l15] = (bf16_t)(acc1[tt][r] * 0.125f);
    __syncthreads();

    f32x4 acc2[16] = {};
    for (int ks = 0; ks < 2; ++ks) {
        bf16x8 a = *(const bf16x8*)&qb[w * 16 + l15][ks * 32 + quad * 8];
        #pragma unroll
        for (int tt = 0; tt < 16; ++tt) {
            bf16x8 bfr = *(const bf16x8*)&wkT[tt * 16 + l15][ks * 32 + quad * 8];
            acc2[tt] = MFMA16(a, bfr, acc2[tt]);
        }
    }
    size_t base = (size_t)(b * HH + h) * 64;
    #pragma unroll
    for (int tt = 0; tt < 16; ++tt)
        #pragma unroll
        for (int r = 0; r < 4; ++r)
            qt[(base + w * 16 + quad * 4 + r) * 256 + tt * 16 + l15] = (bf16_t)acc2[tt][r];
}

// ---------------------------------------------------------------------------
// Kernel 3: flash attention, v = hit@Wv on the fly; single barrier/subtile.
// ROUND-4-EXACT (measured 98 us, spill-free, VGPR 128). Do not reorder.
// ---------------------------------------------------------------------------
__global__ __launch_bounds__(512) void k3_attn(
    const float* __restrict__ hit, const bf16_t* __restrict__ qt,
    const bf16_t* __restrict__ WvT, bf16_t* __restrict__ nump,
    float* __restrict__ lp)
{
    __shared__ alignas(16) bf16_t hs[2][SUB * 256];   // 2 x 16KB, granule-swizzled
    __shared__ alignas(16) bf16_t vb[2][16 * 512];    // 2 x 16KB v-frag exchange

    const int bid = blockIdx.x;
    const int c  = bid & 31;
    const int hg = (bid >> 5) & 1;
    const int b  = bid >> 6;
    const int t  = threadIdx.x;
    const int w = t >> 6, lane = t & 63;
    const int l31 = lane & 31, hi = lane >> 5;
    const int hl = w >> 1;             // local head 0..3
    const int qh = w & 1;              // q-half owned == dv-half owned
    const int h  = hg * 4 + hl;
    const int bh = b * HH + h;

    bf16x8 qf[16], wf[16];
    {
        const bf16_t* qrow = qt + ((size_t)bh * 64 + qh * 32 + l31) * 256 + hi * 8;
        const bf16_t* wrow = WvT + ((size_t)(h * 64 + qh * 32 + l31)) * 256 + hi * 8;
        #pragma unroll
        for (int ks = 0; ks < 16; ++ks) {
            qf[ks] = *(const bf16x8*)(qrow + ks * 16);
            wf[ks] = *(const bf16x8*)(wrow + ks * 16);
        }
    }

    f32x16 accO = {};   // dv-tile == qh
    f32x16 accX = {};   // dv-tile == 1-qh
    float ls = 0.f;

    const float* hbase = hit + ((size_t)b * Nn + c * CHK) * 256;
    const int row0 = t >> 5, g0 = t & 31;
    const int sw0 = (g0 ^ (row0 & 7)) * 8;
    const int sw1 = (g0 ^ ((row0 + 16) & 7)) * 8;

    float4 pA0, pA1, pB0, pB1;
#define PREFETCH(ss) do { \
        const float* s0_ = hbase + (size_t)(ss) * SUB * 256 + (size_t)row0 * 256 + g0 * 8; \
        pA0 = ((const float4*)s0_)[0]; pA1 = ((const float4*)s0_)[1]; \
        const float* s1_ = s0_ + 16 * 256; \
        pB0 = ((const float4*)s1_)[0]; pB1 = ((const float4*)s1_)[1]; \
    } while (0)

    // prologue: stage subtile 0, prefetch subtile 1
    PREFETCH(0);
    store8(&hs[0][row0 * 256 + sw0], pA0, pA1);
    store8(&hs[0][(row0 + 16) * 256 + sw1], pB0, pB1);
    PREFETCH(1);
    __syncthreads();

    const int xr = l31 & 7;

    for (int s = 0; s < NSUB; ++s) {
        const int cur = s & 1;
        const bf16_t* hrow = &hs[cur][l31 * 256];

        // Fused S and v over the 256-d contraction: one A-read feeds 2 MFMAs.
        f32x16 St = {}, Vt = {};
        #pragma unroll
        for (int ks = 0; ks < 16; ++ks) {
            bf16x8 A = *(const bf16x8*)(hrow + (((2 * ks + hi) ^ xr) * 8));
            Vt = MFMA32(A, wf[ks], Vt);
            St = MFMA32(A, qf[ks], St);
        }

        // stage next subtile into the alternate buffer; prefetch s+2
        if (s + 1 < NSUB) {
            store8(&hs[cur ^ 1][row0 * 256 + sw0], pA0, pA1);
            store8(&hs[cur ^ 1][(row0 + 16) * 256 + sw1], pB0, pB1);
        }
        if (s + 2 < NSUB) PREFETCH(s + 2);

        // exp
        #pragma unroll
        for (int r = 0; r < 16; ++r) {
            float e = __expf(St[r]);
            St[r] = e;
            ls += e;
        }
        bf16x8 Pf[2];
        pack_tile(St, hi, Pf);
        {
            bf16x8 Vf[2];
            pack_tile(Vt, hi, Vf);
            *(bf16x8*)&vb[cur][((hl * 2 + 0) * 2 + qh) * 512 + lane * 8] = Vf[0];
            *(bf16x8*)&vb[cur][((hl * 2 + 1) * 2 + qh) * 512 + lane * 8] = Vf[1];
        }   // Vf dies here (pre-barrier)
        __syncthreads();   // the ONLY barrier in the loop

        {
            bf16x8 vo0 = *(const bf16x8*)&vb[cur][((hl * 2 + 0) * 2 + qh) * 512 + lane * 8];
            bf16x8 vx0 = *(const bf16x8*)&vb[cur][((hl * 2 + 0) * 2 + (1 - qh)) * 512 + lane * 8];
            bf16x8 vo1 = *(const bf16x8*)&vb[cur][((hl * 2 + 1) * 2 + qh) * 512 + lane * 8];
            bf16x8 vx1 = *(const bf16x8*)&vb[cur][((hl * 2 + 1) * 2 + (1 - qh)) * 512 + lane * 8];
            accO = MFMA32(Pf[0], vo0, accO);
            accX = MFMA32(Pf[0], vx0, accX);
            accO = MFMA32(Pf[1], vo1, accO);
            accX = MFMA32(Pf[1], vx1, accX);
        }
    }
#undef PREFETCH

    {
        float lt = ls + __shfl_xor(ls, 32, 64);
        if (hi == 0)
            lp[((size_t)bh * NCH + c) * 64 + qh * 32 + l31] = lt;
    }
    {
        size_t nbase = ((size_t)bh * NCH + c) * 64 * 64;
        #pragma unroll
        for (int r = 0; r < 16; ++r) {
            int q = qh * 32 + (r & 3) + 8 * (r >> 2) + 4 * hi;
            size_t ro = nbase + (size_t)q * 64;
            nump[ro + qh * 32 + l31]       = (bf16_t)accO[r];
            nump[ro + (1 - qh) * 32 + l31] = (bf16_t)accX[r];
        }
    }
}

// ---------------------------------------------------------------------------
// Kernel 3.5 (combine): X[b*64+q][h*64+dv] = (sum_c num) / (sum_c l), bf16.
// grid 128 = bh(64) x qh(2); 256 thr. Coalesced bf16x8 loads.
// ---------------------------------------------------------------------------
__global__ __launch_bounds__(256) void k35_comb(
    const bf16_t* __restrict__ nump, const float* __restrict__ lp,
    bf16_t* __restrict__ X)
{
    const int bh = blockIdx.x >> 1, qhb = blockIdx.x & 1;
    const int b = bh >> 3, h = bh & 7;
    const int t = threadIdx.x;
    const int q = qhb * 32 + (t >> 3), g = t & 7;
    float s8[8] = {};
    float lsum = 0.f;
    #pragma unroll 4
    for (int cc = 0; cc < NCH; ++cc) {
        size_t base = ((size_t)bh * NCH + cc) * 64 + q;
        bf16x8 v = *(const bf16x8*)&nump[base * 64 + g * 8];
        #pragma unroll
        for (int j = 0; j < 8; ++j) s8[j] += (float)v[j];
        lsum += lp[base];
    }
    float inv = 1.0f / lsum;
    bf16x8 o;
    #pragma unroll
    for (int j = 0; j < 8; ++j) o[j] = (bf16_t)(s8[j] * inv);
    *(bf16x8*)&X[((size_t)b * 64 + q) * 512 + h * 64 + g * 8] = o;
}

// ---------------------------------------------------------------------------
// Kernel 4a: H = relu(X @ W1 + b1). K-SPLIT: 4 waves per block each take a
// 128-wide K slice of the same 32x32 tile; partials combined via LDS
// atomicAdd into the verified scr transpose buffer. grid 256 = rt(16) x
// ct(16); 256 thr. 1024 waves total (4x the previous latency hiding).
// ---------------------------------------------------------------------------
__global__ __launch_bounds__(256) void k4a_mlp1(
    const bf16_t* __restrict__ X, const float* __restrict__ W1,
    const float* __restrict__ b1, bf16_t* __restrict__ H)
{
    __shared__ float scr[32 * 33];
    const int rt = blockIdx.x >> 4, ct = blockIdx.x & 15;
    const int t = threadIdx.x;
    const int w = t >> 6, lane = t & 63, l31 = lane & 31, hi = lane >> 5;
    const int colbase = ct * 32;

    for (int i = t; i < 32 * 33; i += 256) scr[i] = 0.f;

    const bf16_t* xrow = X + ((size_t)(rt * 32 + l31)) * 512 + hi * 8;
    f32x16 acc = {};
    #pragma unroll
    for (int k8 = 0; k8 < 8; ++k8) {
        int kc = w * 8 + k8;
        bf16x8 af;
        #pragma unroll
        for (int j = 0; j < 8; ++j)
            af[j] = (bf16_t)W1[(size_t)(kc * 16 + hi * 8 + j) * 512 + colbase + l31];
        bf16x8 bfr = *(const bf16x8*)(xrow + kc * 16);
        acc = MFMA32(af, bfr, acc);
    }
    __syncthreads();   // scr zeroed, all partials ready to merge
    #pragma unroll
    for (int r = 0; r < 16; ++r) {
        int m = (r & 3) + 8 * (r >> 2) + 4 * hi;
        atomicAdd(&scr[m * 33 + l31], acc[r]);
    }
    __syncthreads();
    const float bia = b1[colbase + l31];
    #pragma unroll
    for (int jj = 0; jj < 4; ++jj) {
        int j = w * 4 + jj;   // j-range split across the 4 waves
        float v = scr[l31 * 33 + hi * 16 + j] + bia;
        v = fmaxf(v, 0.f);
        H[((size_t)(rt * 32 + hi * 16 + j)) * 512 + colbase + l31] = (bf16_t)v;
    }
}

// ---------------------------------------------------------------------------
// Kernel 4b: y = H @ W2 + b2 + slots (residual) -> ys (f32). Same K-split
// structure as k4a. grid 128 = b(8) x rtt(2) x ct(8); 256 thr.
// ---------------------------------------------------------------------------
__global__ __launch_bounds__(256) void k4b_gemm(
    const bf16_t* __restrict__ H, const float* __restrict__ W2,
    const float* __restrict__ b2, const float* __restrict__ slots,
    float* __restrict__ ys)
{
    __shared__ float scr[32 * 33];
    const int b = blockIdx.x >> 4, rtt = (blockIdx.x >> 3) & 1, ct = blockIdx.x & 7;
    const int t = threadIdx.x;
    const int w = t >> 6, lane = t & 63, l31 = lane & 31, hi = lane >> 5;
    const int colbase = ct * 32;
    const int rowbase = b * 64 + rtt * 32;

    for (int i = t; i < 32 * 33; i += 256) scr[i] = 0.f;

    const bf16_t* hrow = H + ((size_t)(rowbase + l31)) * 512 + hi * 8;
    f32x16 acc = {};
    #pragma unroll
    for (int k8 = 0; k8 < 8; ++k8) {
        int kc = w * 8 + k8;
        bf16x8 af;
        #pragma unroll
        for (int j = 0; j < 8; ++j)
            af[j] = (bf16_t)W2[(size_t)(kc * 16 + hi * 8 + j) * 256 + colbase + l31];
        bf16x8 bfr = *(const bf16x8*)(hrow + kc * 16);
        acc = MFMA32(af, bfr, acc);
    }
    __syncthreads();
    #pragma unroll
    for (int r = 0; r < 16; ++r) {
        int m = (r & 3) + 8 * (r >> 2) + 4 * hi;
        atomicAdd(&scr[m * 33 + l31], acc[r]);
    }
    __syncthreads();
    const float b2c = b2[colbase + l31];
    #pragma unroll
    for (int jj = 0; jj < 4; ++jj) {
        int j = w * 4 + jj;
        int row = rowbase + hi * 16 + j;
        float v = scr[l31 * 33 + hi * 16 + j] + b2c
                + slots[(size_t)row * 256 + colbase + l31];
        ys[(size_t)row * 256 + colbase + l31] = v;
    }
}

// ---------------------------------------------------------------------------
// Kernel 4c: LN2(ys) -> out. grid 64 x 256 thr; each wave does 2 rows.
// ---------------------------------------------------------------------------
__global__ __launch_bounds__(256) void k4c_ln2(
    const float* __restrict__ ys, const float* __restrict__ g2,
    const float* __restrict__ bb2, float* __restrict__ out)
{
    const int t = threadIdx.x;
    const int w = t >> 6, lane = t & 63;
    float4 gv = *(const float4*)&g2[lane * 4];
    float4 bv = *(const float4*)&bb2[lane * 4];
    #pragma unroll
    for (int rr = 0; rr < 2; ++rr) {
        int row = blockIdx.x * 8 + w * 2 + rr;
        float4 x = *(const float4*)&ys[(size_t)row * 256 + lane * 4];
        float s = x.x + x.y + x.z + x.w;
        for (int m = 1; m < 64; m <<= 1) s += __shfl_xor(s, m, 64);
        float mean = s * (1.0f / 256.0f);
        float dx = x.x - mean, dy = x.y - mean, dz = x.z - mean, dw = x.w - mean;
        float v2 = dx * dx + dy * dy + dz * dz + dw * dw;
        for (int m = 1; m < 64; m <<= 1) v2 += __shfl_xor(v2, m, 64);
        float rs = rsqrtf(v2 * (1.0f / 256.0f) + EPSf);
        float4 o;
        o.x = dx * rs * gv.x + bv.x;
        o.y = dy * rs * gv.y + bv.y;
        o.z = dz * rs * gv.z + bv.z;
        o.w = dw * rs * gv.w + bv.w;
        *(float4*)&out[(size_t)row * 256 + lane * 4] = o;
    }
}

// ---------------------------------------------------------------------------
extern "C" void kernel_launch(void* const* d_in, const int* in_sizes, int n_in,
                              void* d_out, int out_size, void* d_ws, size_t ws_size,
                              hipStream_t stream) {
    (void)in_sizes; (void)n_in; (void)out_size; (void)ws_size;
    const float* slots = (const float*)d_in[0];
    const float* hit   = (const float*)d_in[1];
    const float* g1    = (const float*)d_in[2];
    const float* bb1   = (const float*)d_in[3];
    const float* Wq    = (const float*)d_in[4];
    const float* Wk    = (const float*)d_in[5];
    const float* Wv    = (const float*)d_in[6];
    const float* W1    = (const float*)d_in[7];
    const float* b1v   = (const float*)d_in[8];
    const float* W2    = (const float*)d_in[9];
    const float* b2v   = (const float*)d_in[10];
    const float* g2    = (const float*)d_in[11];
    const float* bb2   = (const float*)d_in[12];
    float* out = (float*)d_out;

    // workspace layout (~19.75 MB):
    // qt 2MB (reused as ys 512KB after k3) | WvT 256KB | nump bf16 16MB |
    // lp 512KB | X 512KB | H 512KB
    char* wsp = (char*)d_ws;
    bf16_t* qt   = (bf16_t*)wsp;
    float*  ys   = (float*) wsp;   // overlays qt (dead after k3_attn)
    bf16_t* WvT  = (bf16_t*)(wsp + (size_t)2097152);
    bf16_t* nump = (bf16_t*)(wsp + (size_t)2359296);
    float*  lp   = (float*) (wsp + (size_t)19136512);
    bf16_t* X    = (bf16_t*)(wsp + (size_t)19660800);
    bf16_t* H    = (bf16_t*)(wsp + (size_t)20185088);

    hipLaunchKernelGGL(k1_qt, dim3(72), dim3(256), 0, stream,
                       slots, g1, bb1, Wq, Wk, Wv, qt, WvT);
    hipLaunchKernelGGL(k3_attn, dim3(Bb * 2 * NCH), dim3(512), 0, stream,
                       hit, qt, WvT, nump, lp);
    hipLaunchKernelGGL(k35_comb, dim3(128), dim3(256), 0, stream,
                       nump, lp, X);
    hipLaunchKernelGGL(k4a_mlp1, dim3(256), dim3(256), 0, stream,
                       X, W1, b1v, H);
    hipLaunchKernelGGL(k4b_gemm, dim3(128), dim3(256), 0, stream,
                       H, W2, b2v, slots, ys);
    hipLaunchKernelGGL(k4c_ln2, dim3(64), dim3(256), 0, stream,
                       ys, g2, bb2, out);
}